// Round 1
// baseline (303.827 us; speedup 1.0000x reference)
//
#include <hip/hip_runtime.h>
#include <math.h>

#define H 18
#define NS 65536
#define AD 4
#define ITERS 6
#define ELITES 64
#define CAP 4096
#define DELTA 16.0f

__device__ __forceinline__ unsigned encf(float f) {
    unsigned u = __float_as_uint(f);
    return (u & 0x80000000u) ? ~u : (u | 0x80000000u);
}
__device__ __forceinline__ float decf(unsigned u) {
    return __uint_as_float((u & 0x80000000u) ? (u & 0x7FFFFFFFu) : ~u);
}
__device__ __forceinline__ float clamp4(float x) {
    return fminf(fmaxf(x, -4.0f), 4.0f);
}

// ---- P: values of the N pi candidates (iteration-invariant) + per-block max
__global__ void k_pi_values(const float* __restrict__ pi, const float* __restrict__ target,
                            float* __restrict__ v, float* __restrict__ blockmax) {
    __shared__ float tgt[H * AD];
    __shared__ float wm[4];
    int tid = threadIdx.x;
    if (tid < H * AD) tgt[tid] = target[tid];
    __syncthreads();
    int n = blockIdx.x * 256 + tid;
    const float4* pi4 = (const float4*)pi;
    float acc = 0.0f;
#pragma unroll
    for (int h = 0; h < H; ++h) {
        float4 p = pi4[(size_t)h * NS + n];
        float c;
        c = p.x - tgt[h * 4 + 0]; acc += c * c;
        c = p.y - tgt[h * 4 + 1]; acc += c * c;
        c = p.z - tgt[h * 4 + 2]; acc += c * c;
        c = p.w - tgt[h * 4 + 3]; acc += c * c;
    }
    float val = -acc;
    v[n] = val;
    float m = val;
    for (int off = 32; off; off >>= 1) m = fmaxf(m, __shfl_xor(m, off));
    if ((tid & 63) == 0) wm[tid >> 6] = m;
    __syncthreads();
    if (tid == 0) blockmax[blockIdx.x] = fmaxf(fmaxf(wm[0], wm[1]), fmaxf(wm[2], wm[3]));
}

// ---- I: reduce pi-max, seed per-iteration max slots, zero counters, init mean
__global__ void k_init(const float* __restrict__ pi, const float* __restrict__ blockmax,
                       unsigned* __restrict__ maxslot, unsigned* __restrict__ counts,
                       float* __restrict__ meanbuf) {
    __shared__ float red[256];
    int tid = threadIdx.x;
    red[tid] = blockmax[tid];
    __syncthreads();
    for (int off = 128; off; off >>= 1) {
        if (tid < off) red[tid] = fmaxf(red[tid], red[tid + off]);
        __syncthreads();
    }
    if (tid < ITERS) { maxslot[tid] = encf(red[0]); counts[tid] = 0u; }
    // mean = pi_actions[:, 0, :]
    if (tid < H * AD) meanbuf[tid] = pi[(size_t)(tid >> 2) * NS * AD + (tid & 3)];
}

// ---- A: cem candidate values for iteration i + atomicMax into this iter's slot
__global__ void k_cem_values(const float* __restrict__ noise_i, const float* __restrict__ target,
                             const float* __restrict__ meanbuf, float scale,
                             float* __restrict__ v, unsigned* __restrict__ maxslot_i) {
    __shared__ float tgt[H * AD];
    __shared__ float mn[H * AD];
    __shared__ float wm[4];
    int tid = threadIdx.x;
    if (tid < H * AD) { tgt[tid] = target[tid]; mn[tid] = meanbuf[tid]; }
    __syncthreads();
    int n = blockIdx.x * 256 + tid;
    const float4* nz4 = (const float4*)noise_i;
    float acc = 0.0f;
#pragma unroll
    for (int h = 0; h < H; ++h) {
        float4 p = nz4[(size_t)h * NS + n];
        float c;
        c = clamp4(mn[h * 4 + 0] + scale * p.x) - tgt[h * 4 + 0]; acc += c * c;
        c = clamp4(mn[h * 4 + 1] + scale * p.y) - tgt[h * 4 + 1]; acc += c * c;
        c = clamp4(mn[h * 4 + 2] + scale * p.z) - tgt[h * 4 + 2]; acc += c * c;
        c = clamp4(mn[h * 4 + 3] + scale * p.w) - tgt[h * 4 + 3]; acc += c * c;
    }
    float val = -acc;
    v[NS + n] = val;
    float m = val;
    for (int off = 32; off; off >>= 1) m = fmaxf(m, __shfl_xor(m, off));
    if ((tid & 63) == 0) wm[tid >> 6] = m;
    __syncthreads();
    if (tid == 0) atomicMax(maxslot_i, encf(fmaxf(fmaxf(wm[0], wm[1]), fmaxf(wm[2], wm[3]))));
}

// ---- B: collect indices with v >= max - DELTA (wave-aggregated atomics)
__global__ void k_collect(const float* __restrict__ v, const unsigned* __restrict__ maxslot_i,
                          unsigned* __restrict__ count_i, unsigned* __restrict__ cand_i) {
    int idx = blockIdx.x * 256 + threadIdx.x;
    float thr = decf(*maxslot_i) - DELTA;
    bool pred = v[idx] >= thr;
    unsigned long long m = __ballot(pred);
    int lane = threadIdx.x & 63;
    int cnt = __popcll(m);
    unsigned base = 0;
    if (lane == 0 && cnt) base = atomicAdd(count_i, (unsigned)cnt);
    base = __shfl(base, 0);
    if (pred) {
        unsigned pos = base + (unsigned)__popcll(m & ((1ull << lane) - 1ull));
        if (pos < CAP) cand_i[pos] = (unsigned)idx;
    }
}

// ---- C: single block: top-64 (bitonic over collected), softmax mean update,
//         write output on last iteration
__global__ void __launch_bounds__(256) k_reduce(
        const float* __restrict__ pi, const float* __restrict__ noise_i,
        const float* __restrict__ v, const unsigned* __restrict__ count_i,
        const unsigned* __restrict__ cand_i, float* __restrict__ meanbuf,
        float scale, int is_last, float* __restrict__ out) {
    __shared__ float lv[CAP];
    __shared__ unsigned li[CAP];
    __shared__ float mnL[H * AD];
    __shared__ float nmL[H * AD];
    __shared__ float w[64];
    __shared__ float red[256];
    __shared__ float Sshared;
    int tid = threadIdx.x;
    unsigned cnt = *count_i;
    if (cnt > CAP) cnt = CAP;
    if (tid < H * AD) mnL[tid] = meanbuf[tid];
    for (unsigned k = tid; k < cnt; k += 256) {
        unsigned idx = cand_i[k];
        lv[k] = v[idx];
        li[k] = idx;
    }
    unsigned P2 = 64;
    while (P2 < cnt) P2 <<= 1;
    for (unsigned k = cnt + tid; k < P2; k += 256) { lv[k] = -INFINITY; li[k] = 0x7FFFFFFFu; }
    __syncthreads();
    // bitonic sort descending, tie-break: lower index first (matches top_k)
    for (unsigned kk = 2; kk <= P2; kk <<= 1) {
        for (unsigned j = kk >> 1; j > 0; j >>= 1) {
            for (unsigned x = tid; x < P2; x += 256) {
                unsigned l = x ^ j;
                if (l > x) {
                    float v0 = lv[x], v1 = lv[l];
                    unsigned i0 = li[x], i1 = li[l];
                    bool gt = (v0 > v1) || (v0 == v1 && i0 < i1);
                    bool desc = ((x & kk) == 0);
                    if (desc ? !gt : gt) { lv[x] = v1; lv[l] = v0; li[x] = i1; li[l] = i0; }
                }
            }
            __syncthreads();
        }
    }
    int E = (cnt < 64u) ? (int)cnt : 64;
    if (tid < 64) w[tid] = (tid < E) ? expf(lv[tid] - lv[0]) : 0.0f;
    __syncthreads();
    if (tid < 64) {
        float s = w[tid];
        for (int off = 32; off; off >>= 1) s += __shfl_xor(s, off);
        if (tid == 0) Sshared = s;
    }
    __syncthreads();
    float invS = 1.0f / (Sshared * (1.0f + 1e-9f));
    int e = tid >> 2, a = tid & 3;
    float we = (e < E) ? w[e] : 0.0f;
    unsigned idx = (e < E) ? li[e] : 0u;
    for (int h = 0; h < H; ++h) {
        float av = 0.0f;
        if (e < E) {
            if (idx < NS) {
                av = pi[((size_t)h * NS + idx) * AD + a];
            } else {
                float nz = noise_i[((size_t)h * NS + (idx - NS)) * AD + a];
                av = clamp4(mnL[h * 4 + a] + scale * nz);
            }
        }
        if (is_last && e == 0) out[h * 4 + a] = av;
        red[tid] = we * av;
        __syncthreads();
        for (int off = 32; off; off >>= 1) {
            if (e < off) red[tid] += red[tid + off * 4];
            __syncthreads();
        }
        if (e == 0) nmL[h * 4 + a] = 0.1f * mnL[h * 4 + a] + 0.9f * (red[tid] * invS);
        __syncthreads();
    }
    if (tid < H * AD) meanbuf[tid] = nmL[tid];
}

extern "C" void kernel_launch(void* const* d_in, const int* in_sizes, int n_in,
                              void* d_out, int out_size, void* d_ws, size_t ws_size,
                              hipStream_t stream) {
    const float* pi     = (const float*)d_in[0];
    const float* noise  = (const float*)d_in[1];
    const float* target = (const float*)d_in[2];
    float* out = (float*)d_out;

    float* ws = (float*)d_ws;
    float* v           = ws;                                  // 2*NS floats
    unsigned* maxslot  = (unsigned*)(v + 2 * NS);             // ITERS
    unsigned* counts   = maxslot + ITERS;                     // ITERS
    float* blockmax    = (float*)(counts + ITERS);            // 256
    unsigned* cand     = (unsigned*)(blockmax + 256);         // ITERS*CAP
    float* meanbuf     = (float*)(cand + ITERS * CAP);        // 72

    k_pi_values<<<256, 256, 0, stream>>>(pi, target, v, blockmax);
    k_init<<<1, 256, 0, stream>>>(pi, blockmax, maxslot, counts, meanbuf);
    for (int i = 0; i < ITERS; ++i) {
        float scale = (i == 0) ? 0.5f : 1.0f;
        const float* noise_i = noise + (size_t)i * H * NS * AD;
        k_cem_values<<<256, 256, 0, stream>>>(noise_i, target, meanbuf, scale, v, maxslot + i);
        k_collect<<<512, 256, 0, stream>>>(v, maxslot + i, counts + i, cand + (size_t)i * CAP);
        k_reduce<<<1, 256, 0, stream>>>(pi, noise_i, v, counts + i, cand + (size_t)i * CAP,
                                        meanbuf, scale, (i == ITERS - 1) ? 1 : 0, out);
    }
}

// Round 2
// 270.426 us; speedup vs baseline: 1.1235x; 1.1235x over previous
//
#include <hip/hip_runtime.h>
#include <math.h>

#define H 18
#define NS 65536
#define AD 4
#define ITERS 6
#define DELTA 16.0f
#define CCAP 2048
#define EB 512

__device__ __forceinline__ unsigned encf(float f) {
    unsigned u = __float_as_uint(f);
    return (u & 0x80000000u) ? ~u : (u | 0x80000000u);
}
__device__ __forceinline__ float decf(unsigned u) {
    return __uint_as_float((u & 0x80000000u) ? (u & 0x7FFFFFFFu) : ~u);
}
__device__ __forceinline__ float clamp4(float x) {
    return fminf(fmaxf(x, -4.0f), 4.0f);
}

// ---- pi candidate values (iteration-invariant) + per-block max; block 0 also
//      seeds per-iter max slots, pilist counter, and the initial mean.
__global__ void k_pi(const float* __restrict__ pi, const float* __restrict__ target,
                     float* __restrict__ v, float* __restrict__ blockmax,
                     unsigned* __restrict__ maxslot, unsigned* __restrict__ pilist_cnt,
                     float* __restrict__ meanbuf) {
    __shared__ float tgt[H * AD];
    __shared__ float wm[4];
    int tid = threadIdx.x;
    if (tid < H * AD) tgt[tid] = target[tid];
    __syncthreads();
    int n = blockIdx.x * 256 + tid;
    const float4* pi4 = (const float4*)pi;
    float acc = 0.0f;
#pragma unroll
    for (int h = 0; h < H; ++h) {
        float4 p = pi4[(size_t)h * NS + n];
        float c;
        c = p.x - tgt[h * 4 + 0]; acc += c * c;
        c = p.y - tgt[h * 4 + 1]; acc += c * c;
        c = p.z - tgt[h * 4 + 2]; acc += c * c;
        c = p.w - tgt[h * 4 + 3]; acc += c * c;
    }
    float val = -acc;
    v[n] = val;
    float m = val;
    for (int off = 32; off; off >>= 1) m = fmaxf(m, __shfl_xor(m, off));
    if ((tid & 63) == 0) wm[tid >> 6] = m;
    __syncthreads();
    if (tid == 0) blockmax[blockIdx.x] = fmaxf(fmaxf(wm[0], wm[1]), fmaxf(wm[2], wm[3]));
    if (blockIdx.x == 0) {
        if (tid < ITERS) maxslot[tid] = encf(-INFINITY);
        if (tid == ITERS) *pilist_cnt = 0u;
        if (tid >= 64 && tid < 64 + H * AD) {
            int t = tid - 64;
            meanbuf[t] = pi[(size_t)(t >> 2) * NS * AD + (t & 3)];  // pi[:,0,:]
        }
    }
}

// ---- cem candidate values for iteration i + atomicMax into this iter's slot
__global__ void k_cem(const float* __restrict__ noise_i, const float* __restrict__ target,
                      const float* __restrict__ meanbuf, float scale,
                      float* __restrict__ v, unsigned* __restrict__ maxslot_i) {
    __shared__ float tgt[H * AD];
    __shared__ float mn[H * AD];
    __shared__ float wm[4];
    int tid = threadIdx.x;
    if (tid < H * AD) { tgt[tid] = target[tid]; mn[tid] = meanbuf[tid]; }
    __syncthreads();
    int n = blockIdx.x * 256 + tid;
    const float4* nz4 = (const float4*)noise_i;
    float acc = 0.0f;
#pragma unroll
    for (int h = 0; h < H; ++h) {
        float4 p = nz4[(size_t)h * NS + n];
        float c;
        c = clamp4(mn[h * 4 + 0] + scale * p.x) - tgt[h * 4 + 0]; acc += c * c;
        c = clamp4(mn[h * 4 + 1] + scale * p.y) - tgt[h * 4 + 1]; acc += c * c;
        c = clamp4(mn[h * 4 + 2] + scale * p.z) - tgt[h * 4 + 2]; acc += c * c;
        c = clamp4(mn[h * 4 + 3] + scale * p.w) - tgt[h * 4 + 3]; acc += c * c;
    }
    float val = -acc;
    v[NS + n] = val;
    float m = val;
    for (int off = 32; off; off >>= 1) m = fmaxf(m, __shfl_xor(m, off));
    if ((tid & 63) == 0) wm[tid >> 6] = m;
    __syncthreads();
    if (tid == 0) atomicMax(maxslot_i, encf(fmaxf(fmaxf(wm[0], wm[1]), fmaxf(wm[2], wm[3]))));
}

// ---- single block: collect (threshold scan) + top-64 bitonic + softmax mean
//      update. Iter 0 additionally caches qualifying pi candidates globally.
__global__ void __launch_bounds__(EB) k_elite(
        const float* __restrict__ pi, const float* __restrict__ noise_i,
        const float* __restrict__ v, const float* __restrict__ blockmax,
        const unsigned* __restrict__ maxslot_i, float* __restrict__ meanbuf,
        unsigned* __restrict__ pilist_idx, float* __restrict__ pilist_val,
        unsigned* __restrict__ pilist_cnt, float scale, int iter, int is_last,
        float* __restrict__ out) {
    __shared__ float lv[CCAP];
    __shared__ unsigned li[CCAP];
    __shared__ float buf[64 * 73];
    __shared__ float red[256];
    __shared__ float mnL[H * AD];
    __shared__ float w[64];
    __shared__ float s_pimax, s_S;
    __shared__ unsigned s_cnt;
    int tid = threadIdx.x;
    if (tid == 0) s_cnt = 0u;
    if (tid < H * AD) mnL[tid] = meanbuf[tid];
    if (tid >= 256 && tid < 512) red[tid - 256] = blockmax[tid - 256];
    __syncthreads();
    if (tid < 64) {
        float m = fmaxf(fmaxf(red[tid], red[tid + 64]), fmaxf(red[tid + 128], red[tid + 192]));
        for (int off = 32; off; off >>= 1) m = fmaxf(m, __shfl_xor(m, off));
        if (tid == 0) s_pimax = m;
    }
    __syncthreads();
    float pimax = s_pimax;
    float vmax = fmaxf(pimax, decf(*maxslot_i));
    float thr = vmax - DELTA;

    // ---- phase 1: collect candidates >= thr into LDS
    const float4* v4 = (const float4*)v;
    if (iter == 0) {
        float pthr = pimax - DELTA;
        for (int k = tid; k < 2 * NS / 4; k += EB) {
            float4 x = v4[k];
            float vals[4] = {x.x, x.y, x.z, x.w};
#pragma unroll
            for (int c = 0; c < 4; ++c) {
                unsigned idx = 4u * k + c;
                float val = vals[c];
                if (val >= thr) {
                    unsigned p = atomicAdd(&s_cnt, 1u);
                    if (p < CCAP) { lv[p] = val; li[p] = idx; }
                }
                if (idx < NS && val >= pthr) {
                    unsigned p = atomicAdd(pilist_cnt, 1u);
                    if (p < CCAP) { pilist_idx[p] = idx; pilist_val[p] = val; }
                }
            }
        }
    } else {
        for (int k = NS / 4 + tid; k < 2 * NS / 4; k += EB) {
            float4 x = v4[k];
            float vals[4] = {x.x, x.y, x.z, x.w};
#pragma unroll
            for (int c = 0; c < 4; ++c) {
                float val = vals[c];
                if (val >= thr) {
                    unsigned p = atomicAdd(&s_cnt, 1u);
                    if (p < CCAP) { lv[p] = val; li[p] = 4u * k + c; }
                }
            }
        }
        unsigned pc = *pilist_cnt;
        if (pc > CCAP) pc = CCAP;
        for (unsigned k = tid; k < pc; k += EB) {
            float val = pilist_val[k];
            if (val >= thr) {
                unsigned p = atomicAdd(&s_cnt, 1u);
                if (p < CCAP) { lv[p] = val; li[p] = pilist_idx[k]; }
            }
        }
    }
    __syncthreads();
    unsigned cnt = s_cnt;
    if (cnt > CCAP) cnt = CCAP;

    // ---- phase 2: bitonic sort descending (tie-break lower index, = top_k)
    unsigned P2 = 64;
    while (P2 < cnt) P2 <<= 1;
    for (unsigned k = cnt + tid; k < P2; k += EB) { lv[k] = -INFINITY; li[k] = 0x7FFFFFFFu; }
    __syncthreads();
    for (unsigned kk = 2; kk <= P2; kk <<= 1) {
        for (unsigned j = kk >> 1; j > 0; j >>= 1) {
            for (unsigned x = tid; x < P2; x += EB) {
                unsigned l = x ^ j;
                if (l > x) {
                    float v0 = lv[x], v1 = lv[l];
                    unsigned i0 = li[x], i1 = li[l];
                    bool gt = (v0 > v1) || (v0 == v1 && i0 < i1);
                    bool desc = ((x & kk) == 0);
                    if (desc ? !gt : gt) { lv[x] = v1; lv[l] = v0; li[x] = i1; li[l] = i0; }
                }
            }
            __syncthreads();
        }
    }
    int E = (cnt < 64u) ? (int)cnt : 64;

    // ---- phase 3: softmax weights + sum (one wave)
    if (tid < 64) {
        float we = (tid < E) ? expf(lv[tid] - lv[0]) : 0.0f;
        w[tid] = we;
        float s = we;
        for (int off = 32; off; off >>= 1) s += __shfl_xor(s, off);
        if (tid == 0) s_S = s;
    }
    __syncthreads();
    float invS = 1.0f / (s_S * (1.0f + 1e-9f));

    // ---- phase 4: gather elite actions (batched loads, one latency exposure)
    if (tid < 256) {
        int e = tid >> 2, a = tid & 3;
        float av[H];
        unsigned idx = (e < E) ? li[e] : 0u;
        if (e < E) {
            if (idx < NS) {
#pragma unroll
                for (int h = 0; h < H; ++h)
                    av[h] = pi[(size_t)h * NS * AD + (size_t)idx * AD + a];
            } else {
                unsigned m = idx - NS;
#pragma unroll
                for (int h = 0; h < H; ++h)
                    av[h] = noise_i[(size_t)h * NS * AD + (size_t)m * AD + a];
#pragma unroll
                for (int h = 0; h < H; ++h)
                    av[h] = clamp4(mnL[h * 4 + a] + scale * av[h]);
            }
        } else {
#pragma unroll
            for (int h = 0; h < H; ++h) av[h] = 0.0f;
        }
        if (is_last && e == 0) {
#pragma unroll
            for (int h = 0; h < H; ++h) out[h * 4 + a] = av[h];
        }
        float we = (e < E) ? w[e] : 0.0f;
#pragma unroll
        for (int h = 0; h < H; ++h) buf[e * 73 + h * 4 + a] = we * av[h];
    }
    __syncthreads();

    // ---- phase 5: reduce over elites, momentum update
    if (tid < H * AD) {
        float s = 0.0f;
#pragma unroll 8
        for (int e = 0; e < 64; ++e) s += buf[e * 73 + tid];
        meanbuf[tid] = 0.1f * mnL[tid] + 0.9f * (s * invS);
    }
}

extern "C" void kernel_launch(void* const* d_in, const int* in_sizes, int n_in,
                              void* d_out, int out_size, void* d_ws, size_t ws_size,
                              hipStream_t stream) {
    const float* pi     = (const float*)d_in[0];
    const float* noise  = (const float*)d_in[1];
    const float* target = (const float*)d_in[2];
    float* out = (float*)d_out;

    float* ws = (float*)d_ws;
    float* v            = ws;                                   // 2*NS
    float* blockmax     = v + 2 * NS;                           // 256
    unsigned* maxslot   = (unsigned*)(blockmax + 256);          // 8 (6 used)
    unsigned* pilist_cnt= maxslot + 8;                          // 8 (1 used)
    float* meanbuf      = (float*)(pilist_cnt + 8);             // 72 (+pad)
    unsigned* pilist_idx= (unsigned*)(meanbuf + 80);            // CCAP
    float* pilist_val   = (float*)(pilist_idx + CCAP);          // CCAP

    k_pi<<<256, 256, 0, stream>>>(pi, target, v, blockmax, maxslot, pilist_cnt, meanbuf);
    for (int i = 0; i < ITERS; ++i) {
        float scale = (i == 0) ? 0.5f : 1.0f;
        const float* noise_i = noise + (size_t)i * H * NS * AD;
        k_cem<<<256, 256, 0, stream>>>(noise_i, target, meanbuf, scale, v, maxslot + i);
        k_elite<<<1, EB, 0, stream>>>(pi, noise_i, v, blockmax, maxslot + i, meanbuf,
                                      pilist_idx, pilist_val, pilist_cnt, scale, i,
                                      (i == ITERS - 1) ? 1 : 0, out);
    }
}